// Round 2
// baseline (599.194 us; speedup 1.0000x reference)
//
#include <hip/hip_runtime.h>

// CustomConv2d: 3x3 conv, stride 1, pad 1. B=32, Cin=128, H=W=56, Cout=256.
// fp32 in/out (round-1 NaN proved it); per-wave dtype self-detection keeps
// robustness without a separate serialized detect dispatch.
//
// Implicit GEMM, internally bf16. M=cout(256), N=b*h*w(100352), K=cin*9(1152).
// Round-7: round-6's 8-wave/128x64-tile 8-phase schedule stalled at 25%
// MfmaUtil because LDS fragment reads (~770 cyc/CU/phase) ~= MFMA time
// (620 cyc) and the lockstep barriers serialize them. Fix: fatter wave
// tiles + cross-block overlap.
//   - 4 waves (256 thr), wave tile 128x128: 16 ds_read_b128 per 64 MFMA
//     (0.25 KB/MFMA, was 0.375) -> per CU per half MFMA 2480 cyc/SIMD vs
//     LDS 1500 cyc: MFMA-bound for the first time
//   - 2-deep LDS double buffer, 32KB/half, 64KB total -> 2 blocks/CU;
//     independent blocks fill each other's read/stage/drain bubbles
//   - 1 barrier per half (stage h+1 writes the buffer read at h-1, whose
//     reads retired before the h-1 closing barrier)
//   - stage loads issued a full half (~2500 cyc) before their vmcnt gate
//   - same XOR chunk swizzle (measured 0 bank conflicts)

typedef __attribute__((ext_vector_type(8))) short short8;
typedef __attribute__((ext_vector_type(4))) float floatx4;

typedef __attribute__((address_space(1))) const void* gas_ptr;
typedef __attribute__((address_space(3))) void* las_ptr;

__device__ static inline void gl2lds16(const void* g, void* l) {
    __builtin_amdgcn_global_load_lds((gas_ptr)g, (las_ptr)l, 16, 0, 0);
}

__device__ static inline float bf2f(unsigned short u) {
    union { unsigned int i; float f; } x; x.i = ((unsigned int)u) << 16; return x.f;
}
__device__ static inline unsigned short f2bf(float f) {
    union { float f; unsigned int i; } x; x.f = f;
    unsigned int r = (x.i + 0x7FFFu + ((x.i >> 16) & 1u)) >> 16;  // RNE
    return (unsigned short)r;
}

// Per-wave dtype sniff: low halves of fp32 words are random mantissa bits
// (~19% plausible bf16 exponents); true bf16 data is ~100% plausible.
// Uniform across the wave via ballot; requires all 64 lanes active.
__device__ static inline bool wave_detect_bf16(const unsigned int* __restrict__ p) {
    const int lane = threadIdx.x & 63;
    int cnt = 0;
#pragma unroll
    for (int r = 0; r < 4; ++r) {
        unsigned int w = p[r * 64 + lane];
        unsigned short lo = (unsigned short)(w & 0xFFFFu);
        int e = (lo >> 7) & 0xFF;
        bool plaus = (lo == 0) || (e >= 96 && e <= 144);
        cnt += (int)__popcll(__ballot(plaus));
    }
    return cnt >= 205;   // >=80% of 256 sampled halves
}

// ---------------- weight repack -> [9][256][128] bf16 ----------------------
__global__ void wt_repack(const void* __restrict__ wsrc,
                          unsigned short* __restrict__ wt) {
    const bool isbf = wave_detect_bf16((const unsigned int*)wsrc);
    int idx = blockIdx.x * 256 + threadIdx.x;       // 294912 total, grid=1152
    int ci  = idx & 127;
    int co  = (idx >> 7) & 255;
    int off = idx >> 15;                            // 0..8 = dh*3+dw
    size_t s = (size_t)(co * 128 + ci) * 9 + off;
    float v = isbf ? bf2f(((const unsigned short*)wsrc)[s])
                   : ((const float*)wsrc)[s];
    wt[idx] = f2bf(v);
}

// ------- x NCHW -> padded NHWC bf16 [32][58][58][128], LDS transpose -------
__global__ __launch_bounds__(256) void x_repack(
    const void* __restrict__ xsrc, unsigned short* __restrict__ xp) {
    __shared__ unsigned short tile[56 * 130];   // pad 130: conflict-free
    const int bh  = blockIdx.x;                 // 32*58 blocks
    const int b   = bh / 58, hp = bh - b * 58;  // hp in [0,58)
    const int tid = threadIdx.x;
    unsigned short* row = xp + (size_t)(b * 58 + hp) * 58 * 128;
    if (hp == 0 || hp == 57) {                  // top/bottom pad rows
        uint4 z; z.x = z.y = z.z = z.w = 0u;
        uint4* r = (uint4*)row;
        for (int t = tid; t < 928; t += 256) r[t] = z;
        return;
    }
    const bool isbf = wave_detect_bf16((const unsigned int*)xsrc);
    const int h = hp - 1;
    if (isbf) {
        const unsigned short* xs =
            (const unsigned short*)xsrc + (size_t)b * 128 * 3136 + h * 56;
#pragma unroll
        for (int it = 0; it < 7; ++it) {        // 1792 items = 128ci x 14 w4
            int idx = it * 256 + tid;
            int ci = idx / 14, w4 = idx - ci * 14;
            ushort4 v = *(const ushort4*)(xs + (size_t)ci * 3136 + w4 * 4);
            tile[(w4 * 4 + 0) * 130 + ci] = v.x;
            tile[(w4 * 4 + 1) * 130 + ci] = v.y;
            tile[(w4 * 4 + 2) * 130 + ci] = v.z;
            tile[(w4 * 4 + 3) * 130 + ci] = v.w;
        }
    } else {
        const float* xs = (const float*)xsrc + (size_t)b * 128 * 3136 + h * 56;
#pragma unroll
        for (int it = 0; it < 7; ++it) {
            int idx = it * 256 + tid;
            int ci = idx / 14, w4 = idx - ci * 14;
            float4 v = *(const float4*)(xs + (size_t)ci * 3136 + w4 * 4);
            tile[(w4 * 4 + 0) * 130 + ci] = f2bf(v.x);
            tile[(w4 * 4 + 1) * 130 + ci] = f2bf(v.y);
            tile[(w4 * 4 + 2) * 130 + ci] = f2bf(v.z);
            tile[(w4 * 4 + 3) * 130 + ci] = f2bf(v.w);
        }
    }
    __syncthreads();
#pragma unroll
    for (int it = 0; it < 4; ++it) {
        int k = it * 256 + tid;                 // 928 chunks of 16B
        if (k >= 928) break;
        int wq = k >> 4, cc = k & 15;
        uint4 v;
        if (wq == 0 || wq == 57) { v.x = v.y = v.z = v.w = 0u; }
        else {
            const unsigned short* p = &tile[(wq - 1) * 130 + cc * 8];
            union { unsigned short s[8]; uint4 u; } pk;
#pragma unroll
            for (int j = 0; j < 8; ++j) pk.s[j] = p[j];
            v = pk.u;
        }
        *(uint4*)(row + wq * 128 + cc * 8) = v;
    }
}

// -------- main: 4-wave 128x128-per-wave implicit GEMM, 256x256 tile --------
// K decomposition: 36 "halves" h = off*4 + q; off=h>>2 (0..8 = dh*3+dw),
// k-range within off = q*32 (q = h&3). Half-buffer (32KB): A[256 cout][32k]
// bf16 at +0, B[256 n][32k] bf16 at +16384. Rows are 64B; phys 16B chunk p
// of row r holds logical k-chunk p ^ ((r>>1)&3) (writer clg / reader ph XOR).
__global__ __launch_bounds__(256, 2) void conv_mfma(
    const unsigned short* __restrict__ xp,   // [32][58][58][128] bf16
    const unsigned short* __restrict__ wt,   // [9][256][128] bf16
    const void* __restrict__ bias,           // [256] fp32 or bf16
    void* __restrict__ out,                  // [32][256][56][56] fp32 or bf16
    const void* __restrict__ xorig)          // for dtype sniff only
{
    __shared__ __align__(16) char lds[65536];   // 2 half-buffers x 32KB
    const int tid   = threadIdx.x;
    const int lane  = tid & 63;
    const int wv    = tid >> 6;        // 0..3
    const int ntile = blockIdx.x;      // 0..391 (spatial, 256 cols each)

    const bool isbf = wave_detect_bf16((const unsigned int*)xorig);

    // ---------------- staging setup (8 x 1KB chunks per wave per half) ----
    // Half = 32 chunks (A:16, B:16). Wave wv stages A chunks wv*4+s and
    // B chunks wv*4+s (s=0..3). Chunk c covers LDS rows [c*16, c*16+16);
    // lane writes row c*16 + (lane>>2), phys 16B slot lane&3, whose content
    // is logical k-chunk clg = (lane&3) ^ ((lane>>3)&3).
    const int clg  = (lane & 3) ^ ((lane >> 3) & 3);
    const int rsub = lane >> 2;
    unsigned sbA[4], sbB[4];
    int dbA[4], dbB[4];
#pragma unroll
    for (int s = 0; s < 4; ++s) {
        const int c  = wv * 4 + s;
        const int co = c * 16 + rsub;
        sbA[s] = (unsigned)(co * 256 + clg * 16);          // byte into wt
        dbA[s] = c * 1024;
        const int n = ntile * 256 + c * 16 + rsub;
        const int b = n / 3136, rem = n - b * 3136;
        const int hh = rem / 56, ww = rem - hh * 56;
        sbB[s] = (unsigned)(((b * 58 + hh) * 58 + ww) * 256 + clg * 16);
        dbB[s] = 16384 + c * 1024;
    }

    // ---------------- fragment read setup --------------------------------
    const int fr = lane & 15;
    const int ph = (lane >> 4) ^ ((fr >> 1) & 3);
    const int wm = wv >> 1;            // 0..1  (M: 128 couts per wave)
    const int wn = wv & 1;             // 0..1  (N: 128 cols per wave)
    const int aOff = (wm * 128 + fr) * 64 + ph * 16;          // + i*1024
    const int bOff = 16384 + (wn * 128 + fr) * 64 + ph * 16;  // + j*1024

    floatx4 acc[8][8] = {};

    // ---------------- prologue: stage half 0 into buffer 0 ----------------
#pragma unroll
    for (int s = 0; s < 4; ++s)
        gl2lds16((const char*)wt + sbA[s], lds + dbA[s]);
#pragma unroll
    for (int s = 0; s < 4; ++s)
        gl2lds16((const char*)xp + sbB[s], lds + dbB[s]);
    __builtin_amdgcn_s_waitcnt(0x3F70);   // vmcnt(0): half 0 landed
    __builtin_amdgcn_s_barrier();

    // ---------------- main loop: 36 halves ---------------------------------
#pragma unroll 2
    for (int h = 0; h < 36; ++h) {
        const char* la = lds + (h & 1) * 32768;
        // stage h+1 into the other buffer (read at h-1, retired before the
        // h-1 closing barrier). Issued first: a full half of compute hides
        // the load latency before the vmcnt(0) gate below.
        if (h < 35) {
            char* sd = lds + ((h + 1) & 1) * 32768;
            const int hn  = h + 1;
            const int off = hn >> 2, q = hn & 3;
            const int dA  = off * 65536 + q * 64;
            const int dh_ = off / 3, dw_ = off - dh_ * 3;
            const int dB  = (dh_ * 58 + dw_) * 256 + q * 64;
#pragma unroll
            for (int s = 0; s < 4; ++s)
                gl2lds16((const char*)wt + sbA[s] + dA, sd + dbA[s]);
#pragma unroll
            for (int s = 0; s < 4; ++s)
                gl2lds16((const char*)xp + sbB[s] + dB, sd + dbB[s]);
        }
        short8 af[8], bf[8];
#pragma unroll
        for (int i = 0; i < 8; ++i)
            af[i] = *(const short8*)(la + aOff + i * 1024);
#pragma unroll
        for (int j = 0; j < 8; ++j)
            bf[j] = *(const short8*)(la + bOff + j * 1024);
        __builtin_amdgcn_s_setprio(1);
#pragma unroll
        for (int i = 0; i < 8; ++i)
#pragma unroll
            for (int j = 0; j < 8; ++j)
                acc[i][j] = __builtin_amdgcn_mfma_f32_16x16x32_bf16(
                    af[i], bf[j], acc[i][j], 0, 0, 0);
        __builtin_amdgcn_s_setprio(0);
        if (h < 35) {
            __builtin_amdgcn_s_waitcnt(0x3F70);   // vmcnt(0): h+1 staged
            __builtin_amdgcn_s_barrier();
        }
    }

    // ---- epilogue: D[row=cout(quad*4+reg)][col=spatial(lane&15)] ----------
    const int q4 = (lane >> 4) << 2;
    int nb[8], ns[8];
#pragma unroll
    for (int j = 0; j < 8; ++j) {
        const int n = ntile * 256 + wn * 128 + j * 16 + fr;
        nb[j] = n / 3136;
        ns[j] = n - nb[j] * 3136;
    }
#pragma unroll
    for (int i = 0; i < 8; ++i) {
        const int co = wm * 128 + i * 16 + q4;
        float bv[4];
        if (isbf) {
            const ushort4 bb = *(const ushort4*)((const unsigned short*)bias + co);
            bv[0] = bf2f(bb.x); bv[1] = bf2f(bb.y);
            bv[2] = bf2f(bb.z); bv[3] = bf2f(bb.w);
        } else {
            const float4 bb = *(const float4*)((const float*)bias + co);
            bv[0] = bb.x; bv[1] = bb.y; bv[2] = bb.z; bv[3] = bb.w;
        }
#pragma unroll
        for (int j = 0; j < 8; ++j) {
#pragma unroll
            for (int r = 0; r < 4; ++r) {
                const float v = acc[i][j][r] + bv[r];
                const size_t o = (size_t)nb[j] * 802816 +
                                 (size_t)(co + r) * 3136 + ns[j];
                if (isbf) ((unsigned short*)out)[o] = f2bf(v);
                else      ((float*)out)[o] = v;
            }
        }
    }
}

// ---------------- fallback: naive direct conv fp32 (if ws too small) -------
__global__ void conv_naive(const float* __restrict__ x,
                           const float* __restrict__ w,
                           const float* __restrict__ bias,
                           float* __restrict__ out) {
    long long i = (long long)blockIdx.x * 256 + threadIdx.x;
    if (i >= 25690112LL) return;
    int wo = (int)(i % 56); long long t = i / 56;
    int ho = (int)(t % 56); t /= 56;
    int co = (int)(t % 256); int b = (int)(t / 256);
    float acc = bias[co];
    for (int ci = 0; ci < 128; ++ci)
        for (int dh = 0; dh < 3; ++dh) {
            int hi = ho + dh - 1; if ((unsigned)hi >= 56u) continue;
            for (int dw = 0; dw < 3; ++dw) {
                int wi = wo + dw - 1; if ((unsigned)wi >= 56u) continue;
                acc += x[((size_t)(b * 128 + ci) * 56 + hi) * 56 + wi] *
                       w[((co * 128 + ci) * 3 + dh) * 3 + dw];
            }
        }
    out[i] = acc;
}

extern "C" void kernel_launch(void* const* d_in, const int* in_sizes, int n_in,
                              void* d_out, int out_size, void* d_ws, size_t ws_size,
                              hipStream_t stream) {
    const void* x    = d_in[0];
    const void* w    = d_in[1];
    const void* bias = d_in[2];
    // d_in[3] = approximate (scalar, does not affect exact math) — unused.

    const size_t xp_bytes = (size_t)32 * 58 * 58 * 128 * 2;   // 27,557,888
    const size_t wt_off   = xp_bytes;
    const size_t wt_bytes = (size_t)9 * 256 * 128 * 2;        // 589,824
    const size_t need     = wt_off + wt_bytes;

    if (ws_size >= need) {
        unsigned short* xp = (unsigned short*)d_ws;
        unsigned short* wt = (unsigned short*)((char*)d_ws + wt_off);
        x_repack<<<32 * 58, 256, 0, stream>>>(x, xp);
        wt_repack<<<1152, 256, 0, stream>>>(w, wt);
        conv_mfma<<<dim3(392, 1, 1), 256, 0, stream>>>(xp, wt, bias, d_out, x);
    } else {
        conv_naive<<<(25690112 + 255) / 256, 256, 0, stream>>>(
            (const float*)x, (const float*)w, (const float*)bias, (float*)d_out);
    }
}

// Round 4
// 210.625 us; speedup vs baseline: 2.8448x; 2.8448x over previous
//
#include <hip/hip_runtime.h>

// CustomConv2d: 3x3 conv, stride 1, pad 1. B=32, Cin=128, H=W=56, Cout=256.
// fp32 in/out (round-1 NaN proved it); per-wave dtype self-detection keeps
// robustness without a separate serialized detect dispatch.
//
// Implicit GEMM, internally bf16. M=cout(256), N=b*h*w(100352), K=cin*9(1152).
// Round-9: identical to round-8 (the bench infra failed before running it;
// audit found no deadlock/OOB/race — see session notes). Structure:
//   - wave tile 128x64: acc[8][4]=128 VGPR + frags 48 + addr ~30 => ~210,
//     fits the 256 cap with margin (VGPR_Count is the checkpoint)
//   - block 256x128 (4 waves, 2M x 2N), 784 blocks, XCD-swizzled (784=8x98)
//     so each XCD's contiguous 98 ntiles keep a ~3.5MB xp slice L2-resident
//   - per wave per half: 12 ds_read_b128 vs 32 MFMA (620cyc) - 2x better
//     read:MFMA ratio than round-6's 8-wave phase structure
//   - 3-deep LDS pipeline (24KB/half x3 = 72KB) -> 2 blocks/CU; the two
//     UNSYNCHRONIZED blocks fill each other's barrier/read bubbles
//   - counted vmcnt(6) gate (h+1 landed, h+2 in flight), vmcnt(0) only at
//     the tail; one s_barrier per half
//   - same XOR chunk swizzle (measured 0 bank conflicts)

typedef __attribute__((ext_vector_type(8))) short short8;
typedef __attribute__((ext_vector_type(4))) float floatx4;

typedef __attribute__((address_space(1))) const void* gas_ptr;
typedef __attribute__((address_space(3))) void* las_ptr;

__device__ static inline void gl2lds16(const void* g, void* l) {
    __builtin_amdgcn_global_load_lds((gas_ptr)g, (las_ptr)l, 16, 0, 0);
}

__device__ static inline float bf2f(unsigned short u) {
    union { unsigned int i; float f; } x; x.i = ((unsigned int)u) << 16; return x.f;
}
__device__ static inline unsigned short f2bf(float f) {
    union { float f; unsigned int i; } x; x.f = f;
    unsigned int r = (x.i + 0x7FFFu + ((x.i >> 16) & 1u)) >> 16;  // RNE
    return (unsigned short)r;
}

// Per-wave dtype sniff: low halves of fp32 words are random mantissa bits
// (~19% plausible bf16 exponents); true bf16 data is ~100% plausible.
// Uniform across the wave via ballot; requires all 64 lanes active.
__device__ static inline bool wave_detect_bf16(const unsigned int* __restrict__ p) {
    const int lane = threadIdx.x & 63;
    int cnt = 0;
#pragma unroll
    for (int r = 0; r < 4; ++r) {
        unsigned int w = p[r * 64 + lane];
        unsigned short lo = (unsigned short)(w & 0xFFFFu);
        int e = (lo >> 7) & 0xFF;
        bool plaus = (lo == 0) || (e >= 96 && e <= 144);
        cnt += (int)__popcll(__ballot(plaus));
    }
    return cnt >= 205;   // >=80% of 256 sampled halves
}

// ---------------- weight repack -> [9][256][128] bf16 ----------------------
__global__ void wt_repack(const void* __restrict__ wsrc,
                          unsigned short* __restrict__ wt) {
    const bool isbf = wave_detect_bf16((const unsigned int*)wsrc);
    int idx = blockIdx.x * 256 + threadIdx.x;       // 294912 total, grid=1152
    int ci  = idx & 127;
    int co  = (idx >> 7) & 255;
    int off = idx >> 15;                            // 0..8 = dh*3+dw
    size_t s = (size_t)(co * 128 + ci) * 9 + off;
    float v = isbf ? bf2f(((const unsigned short*)wsrc)[s])
                   : ((const float*)wsrc)[s];
    wt[idx] = f2bf(v);
}

// ------- x NCHW -> padded NHWC bf16 [32][58][58][128], LDS transpose -------
__global__ __launch_bounds__(256) void x_repack(
    const void* __restrict__ xsrc, unsigned short* __restrict__ xp) {
    __shared__ unsigned short tile[56 * 130];   // pad 130: conflict-free
    const int bh  = blockIdx.x;                 // 32*58 blocks
    const int b   = bh / 58, hp = bh - b * 58;  // hp in [0,58)
    const int tid = threadIdx.x;
    unsigned short* row = xp + (size_t)(b * 58 + hp) * 58 * 128;
    if (hp == 0 || hp == 57) {                  // top/bottom pad rows
        uint4 z; z.x = z.y = z.z = z.w = 0u;
        uint4* r = (uint4*)row;
        for (int t = tid; t < 928; t += 256) r[t] = z;
        return;
    }
    const bool isbf = wave_detect_bf16((const unsigned int*)xsrc);
    const int h = hp - 1;
    if (isbf) {
        const unsigned short* xs =
            (const unsigned short*)xsrc + (size_t)b * 128 * 3136 + h * 56;
#pragma unroll
        for (int it = 0; it < 7; ++it) {        // 1792 items = 128ci x 14 w4
            int idx = it * 256 + tid;
            int ci = idx / 14, w4 = idx - ci * 14;
            ushort4 v = *(const ushort4*)(xs + (size_t)ci * 3136 + w4 * 4);
            tile[(w4 * 4 + 0) * 130 + ci] = v.x;
            tile[(w4 * 4 + 1) * 130 + ci] = v.y;
            tile[(w4 * 4 + 2) * 130 + ci] = v.z;
            tile[(w4 * 4 + 3) * 130 + ci] = v.w;
        }
    } else {
        const float* xs = (const float*)xsrc + (size_t)b * 128 * 3136 + h * 56;
#pragma unroll
        for (int it = 0; it < 7; ++it) {
            int idx = it * 256 + tid;
            int ci = idx / 14, w4 = idx - ci * 14;
            float4 v = *(const float4*)(xs + (size_t)ci * 3136 + w4 * 4);
            tile[(w4 * 4 + 0) * 130 + ci] = f2bf(v.x);
            tile[(w4 * 4 + 1) * 130 + ci] = f2bf(v.y);
            tile[(w4 * 4 + 2) * 130 + ci] = f2bf(v.z);
            tile[(w4 * 4 + 3) * 130 + ci] = f2bf(v.w);
        }
    }
    __syncthreads();
#pragma unroll
    for (int it = 0; it < 4; ++it) {
        int k = it * 256 + tid;                 // 928 chunks of 16B
        if (k >= 928) break;
        int wq = k >> 4, cc = k & 15;
        uint4 v;
        if (wq == 0 || wq == 57) { v.x = v.y = v.z = v.w = 0u; }
        else {
            const unsigned short* p = &tile[(wq - 1) * 130 + cc * 8];
            union { unsigned short s[8]; uint4 u; } pk;
#pragma unroll
            for (int j = 0; j < 8; ++j) pk.s[j] = p[j];
            v = pk.u;
        }
        *(uint4*)(row + wq * 128 + cc * 8) = v;
    }
}

// -------- main: 4-wave 128x64-per-wave implicit GEMM, 256x128 tile ---------
// K decomposition: 36 "halves" h = off*4 + q; off=h>>2 (0..8 = dh*3+dw),
// k-range within off = q*32 (q = h&3). Half-buffer (24KB): A[256 cout][32k]
// bf16 at +0 (16KB), B[128 n][32k] bf16 at +16384 (8KB). Rows are 64B; phys
// 16B chunk p of row r holds logical k-chunk p ^ ((r>>1)&3).
__global__ __launch_bounds__(256, 2) void conv_mfma(
    const unsigned short* __restrict__ xp,   // [32][58][58][128] bf16
    const unsigned short* __restrict__ wt,   // [9][256][128] bf16
    const void* __restrict__ bias,           // [256] fp32 or bf16
    void* __restrict__ out,                  // [32][256][56][56] fp32 or bf16
    const void* __restrict__ xorig)          // for dtype sniff only
{
    __shared__ __align__(16) char lds[73728];   // 3 half-buffers x 24KB
    const int tid   = threadIdx.x;
    const int lane  = tid & 63;
    const int wv    = tid >> 6;        // 0..3
    // XCD-aware bijective swizzle (784 = 8 x 98): each XCD gets 98
    // contiguous ntiles -> its xp slice (~3.5MB) stays L2-resident.
    const int bid   = blockIdx.x;
    const int ntile = (bid & 7) * 98 + (bid >> 3);   // 0..783

    const bool isbf = wave_detect_bf16((const unsigned int*)xorig);

    // ---------------- staging setup (6 x 1KB chunks per wave per half) ----
    // A half = 16 chunks, B half = 8 chunks. Wave wv stages A chunks
    // wv*4+s (s=0..3) and B chunks wv*2+s (s=0..1). Chunk c covers LDS rows
    // [c*16, c*16+16); lane writes row c*16 + (lane>>2), phys 16B slot
    // lane&3, whose content is logical k-chunk clg = (lane&3)^((lane>>3)&3).
    const int clg  = (lane & 3) ^ ((lane >> 3) & 3);
    const int rsub = lane >> 2;
    unsigned sbA[4], sbB[2];
    int dbA[4], dbB[2];
#pragma unroll
    for (int s = 0; s < 4; ++s) {
        const int c  = wv * 4 + s;
        const int co = c * 16 + rsub;
        sbA[s] = (unsigned)(co * 256 + clg * 16);          // byte into wt
        dbA[s] = c * 1024;
    }
#pragma unroll
    for (int s = 0; s < 2; ++s) {
        const int c = wv * 2 + s;
        const int n = ntile * 128 + c * 16 + rsub;
        const int b = n / 3136, rem = n - b * 3136;
        const int hh = rem / 56, ww = rem - hh * 56;
        sbB[s] = (unsigned)(((b * 58 + hh) * 58 + ww) * 256 + clg * 16);
        dbB[s] = 16384 + c * 1024;
    }

    // ---------------- fragment read setup --------------------------------
    const int fr = lane & 15;
    const int ph = (lane >> 4) ^ ((fr >> 1) & 3);
    const int wm = wv >> 1;            // 0..1  (M: 128 couts per wave)
    const int wn = wv & 1;             // 0..1  (N: 64 cols per wave)
    const int aOff = (wm * 128 + fr) * 64 + ph * 16;          // + i*1024
    const int bOff = 16384 + (wn * 64 + fr) * 64 + ph * 16;   // + j*1024

    floatx4 acc[8][4] = {};

    // ---------------- prologue: stage halves 0,1 ---------------------------
#pragma unroll
    for (int h = 0; h < 2; ++h) {
        char* lb = lds + h * 24576;
        const int q = h & 3;                 // h<2 => off=0
        const int dA  = q * 64;
        const int dB  = q * 64;              // dh=dw=0 for off=0
#pragma unroll
        for (int s = 0; s < 4; ++s)
            gl2lds16((const char*)wt + sbA[s] + dA, lb + dbA[s]);
#pragma unroll
        for (int s = 0; s < 2; ++s)
            gl2lds16((const char*)xp + sbB[s] + dB, lb + dbB[s]);
    }
    __builtin_amdgcn_s_waitcnt(0x3F76);   // vmcnt(6): half 0 landed
    __builtin_amdgcn_s_barrier();

    // ---------------- main loop: 36 halves ---------------------------------
    int bf_ = 0, st_ = 2;                 // h%3, (h+2)%3
#pragma unroll 3
    for (int h = 0; h < 36; ++h) {
        const char* la = lds + bf_ * 24576;
        // stage h+2 into buf (h+2)%3 (read at h-1, retired at h-1's barrier)
        if (h < 34) {
            char* sd = lds + st_ * 24576;
            const int hn  = h + 2;
            const int off = hn >> 2, q = hn & 3;
            const int dA  = off * 65536 + q * 64;
            const int dh_ = off / 3, dw_ = off - dh_ * 3;
            const int dB  = (dh_ * 58 + dw_) * 256 + q * 64;
#pragma unroll
            for (int s = 0; s < 4; ++s)
                gl2lds16((const char*)wt + sbA[s] + dA, sd + dbA[s]);
#pragma unroll
            for (int s = 0; s < 2; ++s)
                gl2lds16((const char*)xp + sbB[s] + dB, sd + dbB[s]);
        }
        short8 af[8], bf[4];
#pragma unroll
        for (int i = 0; i < 8; ++i)
            af[i] = *(const short8*)(la + aOff + i * 1024);
#pragma unroll
        for (int j = 0; j < 4; ++j)
            bf[j] = *(const short8*)(la + bOff + j * 1024);
        __builtin_amdgcn_s_setprio(1);
#pragma unroll
        for (int i = 0; i < 8; ++i)
#pragma unroll
            for (int j = 0; j < 4; ++j)
                acc[i][j] = __builtin_amdgcn_mfma_f32_16x16x32_bf16(
                    af[i], bf[j], acc[i][j], 0, 0, 0);
        __builtin_amdgcn_s_setprio(0);
        // counted gate: h+1 must be resident before next iteration's reads;
        // h+2's 6 loads stay in flight across the barrier.
        if (h < 34) {
            __builtin_amdgcn_s_waitcnt(0x3F76);   // vmcnt(6)
            __builtin_amdgcn_s_barrier();
        } else if (h == 34) {
            __builtin_amdgcn_s_waitcnt(0x3F70);   // vmcnt(0): h35 landed
            __builtin_amdgcn_s_barrier();
        }
        bf_ = (bf_ == 2) ? 0 : bf_ + 1;
        st_ = (st_ == 2) ? 0 : st_ + 1;
    }

    // ---- epilogue: D[row=cout(quad*4+reg)][col=spatial(lane&15)] ----------
    const int q4 = (lane >> 4) << 2;
    int nb[4], ns[4];
#pragma unroll
    for (int j = 0; j < 4; ++j) {
        const int n = ntile * 128 + wn * 64 + j * 16 + fr;
        nb[j] = n / 3136;
        ns[j] = n - nb[j] * 3136;
    }
#pragma unroll
    for (int i = 0; i < 8; ++i) {
        const int co = wm * 128 + i * 16 + q4;
        float bv[4];
        if (isbf) {
            const ushort4 bb = *(const ushort4*)((const unsigned short*)bias + co);
            bv[0] = bf2f(bb.x); bv[1] = bf2f(bb.y);
            bv[2] = bf2f(bb.z); bv[3] = bf2f(bb.w);
        } else {
            const float4 bb = *(const float4*)((const float*)bias + co);
            bv[0] = bb.x; bv[1] = bb.y; bv[2] = bb.z; bv[3] = bb.w;
        }
#pragma unroll
        for (int j = 0; j < 4; ++j) {
#pragma unroll
            for (int r = 0; r < 4; ++r) {
                const float v = acc[i][j][r] + bv[r];
                const size_t o = (size_t)nb[j] * 802816 +
                                 (size_t)(co + r) * 3136 + ns[j];
                if (isbf) ((unsigned short*)out)[o] = f2bf(v);
                else      ((float*)out)[o] = v;
            }
        }
    }
}

// ---------------- fallback: naive direct conv fp32 (if ws too small) -------
__global__ void conv_naive(const float* __restrict__ x,
                           const float* __restrict__ w,
                           const float* __restrict__ bias,
                           float* __restrict__ out) {
    long long i = (long long)blockIdx.x * 256 + threadIdx.x;
    if (i >= 25690112LL) return;
    int wo = (int)(i % 56); long long t = i / 56;
    int ho = (int)(t % 56); t /= 56;
    int co = (int)(t % 256); int b = (int)(t / 256);
    float acc = bias[co];
    for (int ci = 0; ci < 128; ++ci)
        for (int dh = 0; dh < 3; ++dh) {
            int hi = ho + dh - 1; if ((unsigned)hi >= 56u) continue;
            for (int dw = 0; dw < 3; ++dw) {
                int wi = wo + dw - 1; if ((unsigned)wi >= 56u) continue;
                acc += x[((size_t)(b * 128 + ci) * 56 + hi) * 56 + wi] *
                       w[((co * 128 + ci) * 3 + dh) * 3 + dw];
            }
        }
    out[i] = acc;
}

extern "C" void kernel_launch(void* const* d_in, const int* in_sizes, int n_in,
                              void* d_out, int out_size, void* d_ws, size_t ws_size,
                              hipStream_t stream) {
    const void* x    = d_in[0];
    const void* w    = d_in[1];
    const void* bias = d_in[2];
    // d_in[3] = approximate (scalar, does not affect exact math) — unused.

    const size_t xp_bytes = (size_t)32 * 58 * 58 * 128 * 2;   // 27,557,888
    const size_t wt_off   = xp_bytes;
    const size_t wt_bytes = (size_t)9 * 256 * 128 * 2;        // 589,824
    const size_t need     = wt_off + wt_bytes;

    if (ws_size >= need) {
        unsigned short* xp = (unsigned short*)d_ws;
        unsigned short* wt = (unsigned short*)((char*)d_ws + wt_off);
        x_repack<<<32 * 58, 256, 0, stream>>>(x, xp);
        wt_repack<<<1152, 256, 0, stream>>>(w, wt);
        conv_mfma<<<dim3(784, 1, 1), 256, 0, stream>>>(xp, wt, bias, d_out, x);
    } else {
        conv_naive<<<(25690112 + 255) / 256, 256, 0, stream>>>(
            (const float*)x, (const float*)w, (const float*)bias, (float*)d_out);
    }
}